// Round 5
// baseline (16.318 us; speedup 1.0000x reference)
//
#include <hip/hip_runtime.h>
#include <hip/hip_bf16.h>

#define NGRAPH 64
#define NPER   128
#define DIM    256

typedef __attribute__((ext_vector_type(8))) short bf16x8;
typedef __attribute__((ext_vector_type(4))) float f32x4;

__device__ __forceinline__ float bf2f(short s) {
    union { unsigned u; float f; } v; v.u = ((unsigned)(unsigned short)s) << 16;
    return v.f;
}

__device__ __forceinline__ bf16x8 cvt8(const float4 a, const float4 b) {
    __hip_bfloat162 p0 = __float22bfloat162_rn({a.x, a.y});
    __hip_bfloat162 p1 = __float22bfloat162_rn({a.z, a.w});
    __hip_bfloat162 p2 = __float22bfloat162_rn({b.x, b.y});
    __hip_bfloat162 p3 = __float22bfloat162_rn({b.z, b.w});
    union { __hip_bfloat162 h[4]; bf16x8 v; } u;
    u.h[0] = p0; u.h[1] = p1; u.h[2] = p2; u.h[3] = p3;
    return u.v;
}

// softmax-stat merge: (m,se,ws) with se = sum exp(S-m), ws = sum exp(S-m)*S
__device__ __forceinline__ void sm_merge(float& m, float& se, float& ws,
                                         float mo, float seo, float wso) {
    const float M = fmaxf(m, mo);
    const float a = __expf(m - M), b = __expf(mo - M);
    se = a * se + b * seo;
    ws = a * ws + b * wso;
    m = M;
}

// One block per (graph, d-quarter). Computes S = L R^T ONCE; row stats give
// the left gates (row softmax), col stats give the right gates (col softmax =
// row softmax of S^T). Epilogue writes disjoint 64-dim slices of both outputs.
// Gate identity: sigmoid(<Q_i, atten_i>) = sigmoid(sum_j p_ij S_ij).
__global__ __launch_bounds__(1024, 1)
void match_both_kernel(const float* __restrict__ left,
                       const float* __restrict__ right,
                       float* __restrict__ out) {
    __shared__ __align__(16) short Ls[NPER * DIM]; // bf16 swizzled, 64 KB
    __shared__ __align__(16) short Rs[NPER * DIM]; // bf16 swizzled, 64 KB
    __shared__ float rowpart[2][NPER][3];          // per col-half partial row stats
    __shared__ float colpart[8][NPER][3];          // per row-tile partial col stats
    __shared__ float gl[NPER], gr[NPER];           // gates
    __shared__ float red[2][8][64];                // epilogue reduce

    // XCD swizzle: 4 blocks of graph g share (j&7) -> same XCD slot -> L2 reuse.
    const int j  = blockIdx.x;
    const int g  = (((j >> 5) & 7) << 3) | (j & 7);
    const int dq = (j >> 3) & 3;

    const float* Lg = left  + (size_t)g * NPER * DIM;
    const float* Rg = right + (size_t)g * NPER * DIM;

    const int tid = threadIdx.x;

    // ---- stage L and R fp32 -> bf16 LDS (swizzled), 2 batches x 8 loads ----
    #pragma unroll
    for (int b = 0; b < 2; ++b) {
        const float* src_panel = b ? Rg : Lg;
        short* dst_panel = b ? Rs : Ls;
        float4 f[8];
        int row[4], k8[4];
        #pragma unroll
        for (int u = 0; u < 4; ++u) {
            const int cc = u * 1024 + tid;       // panel-local chunk (8 floats)
            row[u] = cc >> 5;
            k8[u]  = cc & 31;
            const float* s = src_panel + row[u] * DIM + k8[u] * 8;
            f[2 * u]     = *(const float4*)(s);
            f[2 * u + 1] = *(const float4*)(s + 4);
        }
        #pragma unroll
        for (int u = 0; u < 4; ++u) {
            const bf16x8 h = cvt8(f[2 * u], f[2 * u + 1]);
            const int byte = row[u] * (DIM * 2) + ((k8[u] * 16) ^ ((row[u] & 7) << 4));
            *(bf16x8*)((char*)dst_panel + byte) = h;
        }
    }
    __syncthreads();

    // ---- S = L R^T: 16 waves = (row-tile 0..7) x (col-half 0..1) ----
    const int wave = tid >> 6;
    const int lane = tid & 63;
    const int t    = wave & 7;           // 16 L-rows
    const int ch   = wave >> 3;          // 64 R-cols
    const int row0 = t * 16;
    const int lr   = lane & 15;
    const int lkb  = (lane >> 4) * 16;

    f32x4 acc[4];
    #pragma unroll
    for (int c = 0; c < 4; ++c) acc[c] = (f32x4){0.f, 0.f, 0.f, 0.f};

    const int arow = row0 + lr;
    const char* aBase = (const char*)Ls + arow * (DIM * 2);
    const int aswz = (arow & 7) << 4;

    #pragma unroll
    for (int ks = 0; ks < 8; ++ks) {
        const bf16x8 a = *(const bf16x8*)(aBase + ((ks * 64 + lkb) ^ aswz));
        #pragma unroll
        for (int c = 0; c < 4; ++c) {
            const int brow = ch * 64 + c * 16 + lr;
            const bf16x8 bb = *(const bf16x8*)((const char*)Rs + brow * (DIM * 2)
                                               + ((ks * 64 + lkb) ^ ((brow & 7) << 4)));
            acc[c] = __builtin_amdgcn_mfma_f32_16x16x32_bf16(a, bb, acc[c], 0, 0, 0);
        }
    }

    // C layout: lane holds S[row0 + (lane>>4)*4 + r][ch*64 + c*16 + (lane&15)]

    // ---- partial ROW stats (left gates), over this wave's 64 cols ----
    #pragma unroll
    for (int r = 0; r < 4; ++r) {
        float m = fmaxf(fmaxf(acc[0][r], acc[1][r]), fmaxf(acc[2][r], acc[3][r]));
        #pragma unroll
        for (int off = 1; off < 16; off <<= 1) m = fmaxf(m, __shfl_xor(m, off, 64));
        float se = 0.f, wsum = 0.f;
        #pragma unroll
        for (int c = 0; c < 4; ++c) {
            const float e = __expf(acc[c][r] - m);
            se += e; wsum += e * acc[c][r];
        }
        #pragma unroll
        for (int off = 1; off < 16; off <<= 1) {
            se   += __shfl_xor(se, off, 64);
            wsum += __shfl_xor(wsum, off, 64);
        }
        if ((lane & 15) == 0) {
            const int rr = row0 + (lane >> 4) * 4 + r;
            rowpart[ch][rr][0] = m; rowpart[ch][rr][1] = se; rowpart[ch][rr][2] = wsum;
        }
    }

    // ---- partial COL stats (right gates), over this wave's 16 rows ----
    #pragma unroll
    for (int c = 0; c < 4; ++c) {
        float m = fmaxf(fmaxf(acc[c][0], acc[c][1]), fmaxf(acc[c][2], acc[c][3]));
        float se = 0.f, wsum = 0.f;
        #pragma unroll
        for (int r = 0; r < 4; ++r) {
            const float e = __expf(acc[c][r] - m);
            se += e; wsum += e * acc[c][r];
        }
        #pragma unroll
        for (int off = 16; off < 64; off <<= 1) {
            const float mo  = __shfl_xor(m, off, 64);
            const float seo = __shfl_xor(se, off, 64);
            const float wso = __shfl_xor(wsum, off, 64);
            sm_merge(m, se, wsum, mo, seo, wso);
        }
        if (lane < 16) {
            const int jj = ch * 64 + c * 16 + lr;
            colpart[t][jj][0] = m; colpart[t][jj][1] = se; colpart[t][jj][2] = wsum;
        }
    }
    __syncthreads();

    // ---- merge partials -> gates ----
    if (tid < NPER) {
        float m = rowpart[0][tid][0], se = rowpart[0][tid][1], wsum = rowpart[0][tid][2];
        sm_merge(m, se, wsum, rowpart[1][tid][0], rowpart[1][tid][1], rowpart[1][tid][2]);
        gl[tid] = 1.f / (1.f + __expf(-(wsum / se)));
    } else if (tid < 2 * NPER) {
        const int jj = tid - NPER;
        float m = colpart[0][jj][0], se = colpart[0][jj][1], wsum = colpart[0][jj][2];
        #pragma unroll
        for (int s = 1; s < 8; ++s)
            sm_merge(m, se, wsum, colpart[s][jj][0], colpart[s][jj][1], colpart[s][jj][2]);
        gr[jj] = 1.f / (1.f + __expf(-(wsum / se)));
    }
    __syncthreads();

    // ---- epilogue: out[side][g][dq*64+d] = sum_i gate[i] * P[i][dq*64+d] ----
    const int side = tid >> 9;            // 0: left, 1: right
    const int d    = tid & 63;
    const int part = (tid >> 6) & 7;      // 8 parts x 16 rows
    const short* P  = side ? Rs : Ls;
    const float* gg = side ? gr : gl;
    const int dgl = dq * 64 + d;
    float sum = 0.f;
    #pragma unroll
    for (int i = part * 16; i < part * 16 + 16; ++i) {
        const short s = *(const short*)((const char*)P + i * (DIM * 2)
                                        + ((2 * dgl) ^ ((i & 7) << 4)));
        sum += gg[i] * bf2f(s);
    }
    red[side][part][d] = sum;
    __syncthreads();
    if (tid < 128) {
        const int sd = tid >> 6, dd = tid & 63;
        float s = 0.f;
        #pragma unroll
        for (int p = 0; p < 8; ++p) s += red[sd][p][dd];
        out[(size_t)sd * (NGRAPH * DIM) + (size_t)g * DIM + dq * 64 + dd] = s;
    }
}

extern "C" void kernel_launch(void* const* d_in, const int* in_sizes, int n_in,
                              void* d_out, int out_size, void* d_ws, size_t ws_size,
                              hipStream_t stream) {
    const float* left  = (const float*)d_in[0];
    const float* right = (const float*)d_in[1];
    float* out = (float*)d_out;
    match_both_kernel<<<256, 1024, 0, stream>>>(left, right, out);
}

// Round 6
// 12.431 us; speedup vs baseline: 1.3127x; 1.3127x over previous
//
#include <hip/hip_runtime.h>
#include <hip/hip_bf16.h>

#define NGRAPH 64
#define NPER   128
#define DIM    256

typedef __attribute__((ext_vector_type(8))) short bf16x8;
typedef __attribute__((ext_vector_type(4))) float f32x4;

__device__ __forceinline__ float bf2f(short s) {
    union { unsigned u; float f; } v; v.u = ((unsigned)(unsigned short)s) << 16;
    return v.f;
}

__device__ __forceinline__ bf16x8 cvt8(const float4 a, const float4 b) {
    __hip_bfloat162 p0 = __float22bfloat162_rn({a.x, a.y});
    __hip_bfloat162 p1 = __float22bfloat162_rn({a.z, a.w});
    __hip_bfloat162 p2 = __float22bfloat162_rn({b.x, b.y});
    __hip_bfloat162 p3 = __float22bfloat162_rn({b.z, b.w});
    union { __hip_bfloat162 h[4]; bf16x8 v; } u;
    u.h[0] = p0; u.h[1] = p1; u.h[2] = p2; u.h[3] = p3;
    return u.v;
}

// One block per (graph, side, d-half). Full 128x128 row softmax for this
// side's query rows -> exact gates; epilogue writes a disjoint 128-dim output
// slice (no atomics, no memset, one kernel node).
// Staging is k-split: half0 (dims 0..127) staged, barrier, then half1 loads
// fly under MFMA ks=0..3, are written, barrier, MFMA ks=4..7.
// Gate identity: sigmoid(<Q_i, atten_i>) = sigmoid(sum_j p_ij S_ij).
__global__ __launch_bounds__(512, 1)
void match_gate_kernel(const float* __restrict__ left,
                       const float* __restrict__ right,
                       float* __restrict__ out) {
    __shared__ __align__(16) short Ls[NPER * DIM]; // bf16 swizzled, 64 KB
    __shared__ __align__(16) short Rs[NPER * DIM]; // bf16 swizzled, 64 KB
    __shared__ float wq[NPER];
    __shared__ float red[4][128];

    // XCD swizzle: the 4 blocks of graph g share (j&7) -> same XCD -> L2 reuse.
    const int j    = blockIdx.x;
    const int g    = (((j >> 5) & 7) << 3) | (j & 7);
    const int sub  = (j >> 3) & 3;
    const int side = sub >> 1;
    const int dh   = sub & 1;

    const float* Lg = left  + (size_t)g * NPER * DIM;
    const float* Rg = right + (size_t)g * NPER * DIM;

    const int tid = threadIdx.x;

    // ---- phase 0: stage k-dims 0..127 of both panels (bf16, XOR-swizzled) --
    // 4096 chunks of 8 floats: u=0..3 -> L panel, u=4..7 -> R panel.
    #pragma unroll
    for (int b = 0; b < 2; ++b) {                 // 2 batches x 4 chunks
        float4 f[8];
        int row[4], k8[4];
        #pragma unroll
        for (int u = 0; u < 4; ++u) {
            const int cc = (b * 4 + u) * 512 + tid;
            row[u] = (cc >> 4) & 127;
            k8[u]  = cc & 15;                     // dims 0..127
            const float* s = (b ? Rg : Lg) + row[u] * DIM + k8[u] * 8;
            f[2 * u]     = *(const float4*)(s);
            f[2 * u + 1] = *(const float4*)(s + 4);
        }
        short* dst = b ? Rs : Ls;
        #pragma unroll
        for (int u = 0; u < 4; ++u) {
            const bf16x8 h = cvt8(f[2 * u], f[2 * u + 1]);
            const int byte = row[u] * (DIM * 2) + ((k8[u] * 16) ^ ((row[u] & 7) << 4));
            *(bf16x8*)((char*)dst + byte) = h;
        }
    }
    __syncthreads();

    const short* Qs = side ? Rs : Ls;
    const short* Ks = side ? Ls : Rs;

    const int wave = tid >> 6;
    const int lane = tid & 63;
    const int row0 = wave * 16;
    const int lr   = lane & 15;
    const int lkb  = (lane >> 4) * 16;

    f32x4 acc[8];
    #pragma unroll
    for (int c = 0; c < 8; ++c) acc[c] = (f32x4){0.f, 0.f, 0.f, 0.f};

    const int arow = row0 + lr;
    const char* aBase = (const char*)Qs + arow * (DIM * 2);
    const int aswz = (arow & 7) << 4;

    auto do_mfma = [&](int ks) {
        const bf16x8 a = *(const bf16x8*)(aBase + ((ks * 64 + lkb) ^ aswz));
        #pragma unroll
        for (int c = 0; c < 8; ++c) {
            const int brow = c * 16 + lr;
            const bf16x8 bb = *(const bf16x8*)((const char*)Ks + brow * (DIM * 2)
                                               + ((ks * 64 + lkb) ^ ((brow & 7) << 4)));
            acc[c] = __builtin_amdgcn_mfma_f32_16x16x32_bf16(a, bb, acc[c], 0, 0, 0);
        }
    };

    // ---- phase 1: half1 loads in flight under MFMA ks=0..3 ----
    {
        float4 fA[8];
        int rA[4], kA[4];
        #pragma unroll
        for (int u = 0; u < 4; ++u) {             // L panel, dims 128..255
            const int cc = u * 512 + tid;
            rA[u] = (cc >> 4) & 127;
            kA[u] = 16 + (cc & 15);
            const float* s = Lg + rA[u] * DIM + kA[u] * 8;
            fA[2 * u]     = *(const float4*)(s);
            fA[2 * u + 1] = *(const float4*)(s + 4);
        }
        do_mfma(0); do_mfma(1);
        #pragma unroll
        for (int u = 0; u < 4; ++u) {
            const bf16x8 h = cvt8(fA[2 * u], fA[2 * u + 1]);
            const int byte = rA[u] * (DIM * 2) + ((kA[u] * 16) ^ ((rA[u] & 7) << 4));
            *(bf16x8*)((char*)Ls + byte) = h;
        }
        float4 fB[8];
        int rB[4], kB[4];
        #pragma unroll
        for (int u = 0; u < 4; ++u) {             // R panel, dims 128..255
            const int cc = (4 + u) * 512 + tid;
            rB[u] = (cc >> 4) & 127;
            kB[u] = 16 + (cc & 15);
            const float* s = Rg + rB[u] * DIM + kB[u] * 8;
            fB[2 * u]     = *(const float4*)(s);
            fB[2 * u + 1] = *(const float4*)(s + 4);
        }
        do_mfma(2); do_mfma(3);
        #pragma unroll
        for (int u = 0; u < 4; ++u) {
            const bf16x8 h = cvt8(fB[2 * u], fB[2 * u + 1]);
            const int byte = rB[u] * (DIM * 2) + ((kB[u] * 16) ^ ((rB[u] & 7) << 4));
            *(bf16x8*)((char*)Rs + byte) = h;
        }
    }
    __syncthreads();

    // ---- phase 2: remaining K, then stats ----
    do_mfma(4); do_mfma(5); do_mfma(6); do_mfma(7);

    // lane holds S[row0 + (lane>>4)*4 + r][c*16 + (lane&15)]
    #pragma unroll
    for (int r = 0; r < 4; ++r) {
        float m = acc[0][r];
        #pragma unroll
        for (int c = 1; c < 8; ++c) m = fmaxf(m, acc[c][r]);
        #pragma unroll
        for (int off = 1; off < 16; off <<= 1) m = fmaxf(m, __shfl_xor(m, off, 64));
        float se = 0.f, wsum = 0.f;
        #pragma unroll
        for (int c = 0; c < 8; ++c) {
            const float e = __expf(acc[c][r] - m);
            se += e; wsum += e * acc[c][r];
        }
        #pragma unroll
        for (int off = 1; off < 16; off <<= 1) {
            se   += __shfl_xor(se, off, 64);
            wsum += __shfl_xor(wsum, off, 64);
        }
        if ((lane & 15) == 0)
            wq[row0 + (lane >> 4) * 4 + r] = 1.f / (1.f + __expf(-(wsum / se)));
    }
    __syncthreads();

    // ---- epilogue: out[dh*128+dd] = sum_i wq[i]*Q[i][dh*128+dd] (LDS bf16) --
    const int dd   = tid & 127;
    const int part = tid >> 7;            // 4 parts x 32 rows
    const int dgl  = dh * 128 + dd;
    float sum = 0.f;
    #pragma unroll 8
    for (int i = part * 32; i < part * 32 + 32; ++i) {
        const short s = *(const short*)((const char*)Qs + i * (DIM * 2)
                                        + ((2 * dgl) ^ ((i & 7) << 4)));
        sum += wq[i] * bf2f(s);
    }
    red[part][dd] = sum;
    __syncthreads();
    if (tid < 128) {
        float* outp = out + (size_t)side * (NGRAPH * DIM) + (size_t)g * DIM + dh * 128;
        outp[tid] = red[0][tid] + red[1][tid] + red[2][tid] + red[3][tid];
    }
}

extern "C" void kernel_launch(void* const* d_in, const int* in_sizes, int n_in,
                              void* d_out, int out_size, void* d_ws, size_t ws_size,
                              hipStream_t stream) {
    const float* left  = (const float*)d_in[0];
    const float* right = (const float*)d_in[1];
    float* out = (float*)d_out;
    match_gate_kernel<<<256, 512, 0, stream>>>(left, right, out);
}